// Round 20
// baseline (485.970 us; speedup 1.0000x reference)
//
#include <hip/hip_runtime.h>
#include <hip/hip_bf16.h>

// B=4, S=2048, D=1024, H=16, HD=64, causal MHA forward, fp32 in/out.
// Pipeline: convert-W -> 3 QKV GEMMs (fp32 A, 2-deep reg prefetch, counted
// vmcnt barriers) -> flash attn v14 (single-V, 5 blocks/CU) -> out GEMM.

#define SLEN 2048
#define DMOD 1024

typedef __attribute__((ext_vector_type(8))) short s16x8;   // 8 bf16 (4 VGPRs)
typedef __attribute__((ext_vector_type(4))) float f32x4;

__device__ __forceinline__ unsigned short f2bf(float f) {
    union { __hip_bfloat16 h; unsigned short u; } cv;
    cv.h = __float2bfloat16(f);
    return cv.u;
}
__device__ __forceinline__ unsigned cvtpk(float a, float b) {
    unsigned r;
    asm("v_cvt_pk_bf16_f32 %0, %1, %2" : "=v"(r) : "v"(a), "v"(b));
    return r;
}
__device__ __forceinline__ void gload_lds16(const void* g, void* l) {
    __builtin_amdgcn_global_load_lds(
        (const __attribute__((address_space(1))) void*)g,
        (__attribute__((address_space(3))) void*)l, 16, 0, 0);
}

// ---------------- fp32 -> bf16 convert (weights only) --------------------
__global__ __launch_bounds__(256) void convert_w(
    const float* __restrict__ wq, const float* __restrict__ wk,
    const float* __restrict__ wv, const float* __restrict__ wo,
    unsigned short* __restrict__ dst)
{
    const int bid = blockIdx.x, tid = threadIdx.x;
    const int w = bid >> 7;
    const float* src = (w == 0) ? wq : (w == 1) ? wk : (w == 2) ? wv : wo;
    unsigned short* d = dst + (size_t)w * 1048576;
    const size_t off = (size_t)(bid & 127) * 8192;
#pragma unroll
    for (int i = 0; i < 8; ++i) {
        const size_t e = off + (size_t)(i * 256 + tid) * 4;
        float4 x = *reinterpret_cast<const float4*>(&src[e]);
        uint2 u;
        u.x = cvtpk(x.x, x.y);
        u.y = cvtpk(x.z, x.w);
        *reinterpret_cast<uint2*>(&d[e]) = u;
    }
}

// ---------------- QKV GEMM v3 (round-16 proven): 2-deep A prefetch -------
template<int MODE>
__global__ __launch_bounds__(256, 2) void gemm_qkv(
    const float* __restrict__ A, const unsigned short* __restrict__ W,
    const float* __restrict__ bias, unsigned short* __restrict__ outp,
    float oscale)
{
    __shared__ unsigned short Asm[2][8192];
    __shared__ unsigned short Bsm[2][8192];

    const int tid  = threadIdx.x;
    const int lane = tid & 63, wid = tid >> 6;
    const int l15 = lane & 15, lhi = lane >> 4;

    const int flat = blockIdx.x;
    const int logical = (flat & 7) * 64 + (flat >> 3);
    const int m0 = (logical >> 3) * 128, n0 = (logical & 7) * 128;
    const int wr = wid >> 1, wc = wid & 1;

    int soff[4];
    const float* aptc[4];
#pragma unroll
    for (int i = 0; i < 4; ++i) {
        const int f = i * 256 + tid;
        const int srow = f >> 3, sg = f & 7;
        soff[i] = srow * 128 + ((sg ^ (srow & 7)) * 16);
        aptc[i] = A + (size_t)(m0 + srow) * 1024 + sg * 8;
    }
    const int wsrow = lane >> 3;
    const int wsgr  = (lane & 7) ^ wsrow;
    const unsigned short* bpt = W + (size_t)(n0 + wid * 8 + wsrow) * 1024 + wsgr * 8;

    int aoff[2][4], boff[2][4];
#pragma unroll
    for (int kk = 0; kk < 2; ++kk)
#pragma unroll
        for (int i = 0; i < 4; ++i) {
            const int s = ((4 * kk + lhi) ^ (l15 & 7)) * 16;
            aoff[kk][i] = (wr * 64 + i * 16 + l15) * 128 + s;
            boff[kk][i] = (wc * 64 + i * 16 + l15) * 128 + s;
        }

    f32x4 acc[4][4];
#pragma unroll
    for (int i = 0; i < 4; ++i)
#pragma unroll
        for (int j = 0; j < 4; ++j) acc[i][j] = (f32x4)0.f;

    float4 awE[8], awO[8];

    auto loadTo = [&](float4 (&aw)[8], int k0) {
#pragma unroll
        for (int i = 0; i < 4; ++i) {
            aw[2 * i]     = *reinterpret_cast<const float4*>(aptc[i] + k0);
            aw[2 * i + 1] = *reinterpret_cast<const float4*>(aptc[i] + k0 + 4);
        }
    };
    auto writeFrom = [&](float4 (&aw)[8], int bsel) {
#pragma unroll
        for (int i = 0; i < 4; ++i) {
            uint4 u;
            u.x = cvtpk(aw[2 * i].x,     aw[2 * i].y);
            u.y = cvtpk(aw[2 * i].z,     aw[2 * i].w);
            u.z = cvtpk(aw[2 * i + 1].x, aw[2 * i + 1].y);
            u.w = cvtpk(aw[2 * i + 1].z, aw[2 * i + 1].w);
            *reinterpret_cast<uint4*>((char*)&Asm[bsel][0] + soff[i]) = u;
        }
    };
    auto stageW = [&](int bsel) {
        char* bd = (char*)Bsm + bsel * 16384 + wid * 1024;
#pragma unroll
        for (int i = 0; i < 4; ++i)
            gload_lds16(bpt + i * 32768, bd + i * 4096);
        bpt += 64;
    };
    auto mfmaPhase = [&](const char* AB, const char* BB) {
#pragma unroll
        for (int kk = 0; kk < 2; ++kk) {
            s16x8 af[4], bfv[4];
#pragma unroll
            for (int i = 0; i < 4; ++i) af[i]  = *reinterpret_cast<const s16x8*>(AB + aoff[kk][i]);
#pragma unroll
            for (int j = 0; j < 4; ++j) bfv[j] = *reinterpret_cast<const s16x8*>(BB + boff[kk][j]);
#pragma unroll
            for (int i = 0; i < 4; ++i)
#pragma unroll
                for (int j = 0; j < 4; ++j)
                    acc[i][j] = __builtin_amdgcn_mfma_f32_16x16x32_bf16(af[i], bfv[j], acc[i][j], 0, 0, 0);
        }
    };
    auto barrier8 = [&]() {
        asm volatile("s_waitcnt vmcnt(8) lgkmcnt(0)" ::: "memory");
        __builtin_amdgcn_s_barrier();
        __builtin_amdgcn_sched_barrier(0);
    };
    auto barrier0 = [&]() {
        asm volatile("s_waitcnt vmcnt(0) lgkmcnt(0)" ::: "memory");
        __builtin_amdgcn_s_barrier();
        __builtin_amdgcn_sched_barrier(0);
    };

    loadTo(awE, 0);
    stageW(0);
    writeFrom(awE, 0);
    loadTo(awO, 64);
    barrier8();

#pragma unroll 1
    for (int kt = 0; kt < 16; kt += 2) {
        if (kt + 1 < 16) stageW(1);
        if (kt + 2 < 16) loadTo(awE, (kt + 2) * 64);
        mfmaPhase((const char*)&Asm[0][0], (const char*)&Bsm[0][0]);
        if (kt + 1 < 16) writeFrom(awO, 1);
        if (kt + 2 < 16) barrier8(); else barrier0();
        if (kt + 2 < 16) stageW(0);
        if (kt + 3 < 16) loadTo(awO, (kt + 3) * 64);
        mfmaPhase((const char*)&Asm[1][0], (const char*)&Bsm[1][0]);
        if (kt + 2 < 16) writeFrom(awE, 0);
        if (kt + 3 < 16) barrier8(); else barrier0();
    }

#pragma unroll
    for (int j = 0; j < 4; ++j) {
        const int col = n0 + wc * 64 + j * 16 + l15;
        const float bv = bias[col];
#pragma unroll
        for (int i = 0; i < 4; ++i) {
#pragma unroll
            for (int r = 0; r < 4; ++r) {
                const int row = m0 + wr * 64 + i * 16 + lhi * 4 + r;
                const float val = (acc[i][j][r] + bv) * oscale;
                if constexpr (MODE == 0) {
                    outp[(size_t)((row >> 11) * 16 + (col >> 6)) * 131072
                         + (size_t)(row & 2047) * 64 + (col & 63)] = f2bf(val);
                } else {
                    outp[(size_t)((row >> 11) * 16 + (col >> 6)) * 131072
                         + (size_t)(col & 63) * 2048 + (row & 2047)] = f2bf(val);
                }
            }
        }
    }
}

// ---------------- out-proj GEMM (bf16 A via DMA, fp32 out) ---------------
__global__ __launch_bounds__(256) void gemm_out(
    const unsigned short* __restrict__ A, const unsigned short* __restrict__ W,
    const float* __restrict__ bias, float* __restrict__ outp)
{
    __shared__ unsigned short Asm[2][8192];
    __shared__ unsigned short Bsm[2][8192];

    const int tid  = threadIdx.x;
    const int lane = tid & 63, wid = tid >> 6;
    const int l15 = lane & 15, lhi = lane >> 4;

    const int flat = blockIdx.x;
    const int logical = (flat & 7) * 64 + (flat >> 3);
    const int m0 = (logical >> 3) * 128, n0 = (logical & 7) * 128;

    const int wr = wid >> 1, wc = wid & 1;
    const int srow = lane >> 3;
    const int sgr  = (lane & 7) ^ srow;

    int aoff[2][4], boff[2][4];
#pragma unroll
    for (int kk = 0; kk < 2; ++kk)
#pragma unroll
        for (int i = 0; i < 4; ++i) {
            const int s = ((4 * kk + lhi) ^ (l15 & 7)) * 16;
            aoff[kk][i] = (wr * 64 + i * 16 + l15) * 128 + s;
            boff[kk][i] = (wc * 64 + i * 16 + l15) * 128 + s;
        }

    const unsigned short* apt = A + (size_t)(m0 + wid * 8 + srow) * 1024 + sgr * 8;
    const unsigned short* bpt = W + (size_t)(n0 + wid * 8 + srow) * 1024 + sgr * 8;

    f32x4 acc[4][4];
#pragma unroll
    for (int i = 0; i < 4; ++i)
#pragma unroll
        for (int j = 0; j < 4; ++j) acc[i][j] = (f32x4)0.f;

    auto stage = [&](int bsel) {
        char* ad = (char*)Asm + bsel * 16384 + wid * 1024;
        char* bd = (char*)Bsm + bsel * 16384 + wid * 1024;
#pragma unroll
        for (int i = 0; i < 4; ++i) {
            gload_lds16(apt + i * 32768, ad + i * 4096);
            gload_lds16(bpt + i * 32768, bd + i * 4096);
        }
        apt += 64; bpt += 64;
    };

    stage(0);
    __syncthreads();
    int cur = 0;
#pragma unroll 1
    for (int kt = 0; kt < 16; ++kt) {
        if (kt < 15) stage(cur ^ 1);
        const char* AB = (const char*)Asm + cur * 16384;
        const char* BB = (const char*)Bsm + cur * 16384;
#pragma unroll
        for (int kk = 0; kk < 2; ++kk) {
            s16x8 af[4], bfv[4];
#pragma unroll
            for (int i = 0; i < 4; ++i) af[i]  = *reinterpret_cast<const s16x8*>(AB + aoff[kk][i]);
#pragma unroll
            for (int j = 0; j < 4; ++j) bfv[j] = *reinterpret_cast<const s16x8*>(BB + boff[kk][j]);
#pragma unroll
            for (int i = 0; i < 4; ++i)
#pragma unroll
                for (int j = 0; j < 4; ++j)
                    acc[i][j] = __builtin_amdgcn_mfma_f32_16x16x32_bf16(af[i], bfv[j], acc[i][j], 0, 0, 0);
        }
        __syncthreads();
        cur ^= 1;
    }

#pragma unroll
    for (int j = 0; j < 4; ++j) {
        const int col = n0 + wc * 64 + j * 16 + l15;
        const float bv = bias[col];
#pragma unroll
        for (int i = 0; i < 4; ++i)
#pragma unroll
            for (int r = 0; r < 4; ++r) {
                const int row = m0 + wr * 64 + i * 16 + lhi * 4 + r;
                outp[(size_t)row * 1024 + col] = acc[i][j][r] + bv;
            }
    }
}

// ---------------- flash attention v14 ------------------------------------
// v10 with SINGLE V buffer (LDS 40K->32K => 5 blocks/CU, +25% TLP):
// per round: issue V(t) DMA then K(t+1) DMA; QK+softmax (covers V latency);
// counted vmcnt + barrier before PV (drains exactly the V pair); PV; end
// barrier (vmcnt 0) drains K prefetch after a full round in flight.
#define EXPC 0.18033688011112043f   // 0.125 * log2(e)

__global__ __launch_bounds__(256, 5) void attn_kernel(
    const unsigned short* __restrict__ Q,
    const unsigned short* __restrict__ Kc,
    const unsigned short* __restrict__ Vt,
    unsigned short* __restrict__ Ao)
{
    // [0,16K): K dbuf (8K each)  [16K,24K): V single  [24K,32K): per-wave P
    __shared__ char smem[32768];

    const int tid = threadIdx.x, lane = tid & 63, wid = tid >> 6;
    const int l15 = lane & 15, lhi = lane >> 4;
    const int sK = l15 & 7;
    const int sub = lane >> 3, c8s = lane & 7;
    const int thr = wid * 16 + l15;

    const int kb0 = l15 * 128 + (lhi ^ sK) * 16;
    const int kb1 = kb0 ^ 64;
    char* const pb0 = smem + 24576 + wid * 2048 + kb0;
    char* const pb1 = smem + 24576 + wid * 2048 + kb1;
    char* const PWp = smem + 24576 + wid * 2048;
    const char* const vr0 = smem + 16384 + kb0;   // V read bases (fixed)
    const char* const vr1 = smem + 16384 + kb1;
    int pw[4];
#pragma unroll
    for (int nb = 0; nb < 4; ++nb)
        pw[nb] = (l15 * 16 + ((nb * 4 + lhi) ^ (2 * sK))) * 8;

    const int flat = blockIdx.x;
    const int logical = (flat & 7) * 128 + (flat >> 3);
    const int bx = logical & 15, bh = logical >> 4;
    const int qtL = bx, qtH = 31 - bx;
    const int q0L = qtL * 64, q0H = qtH * 64;

    const size_t base = (size_t)bh * SLEN * 64;
    const unsigned short* Qb = Q + base;
    const unsigned short* Kb = Kc + base;
    const unsigned short* Vb = Vt + base;      // [64][SLEN]
    const int b = bh >> 4, h = bh & 15;
    const int scol = (c8s ^ sub) * 8;

    const f32x4 fzero = (f32x4)0.f;
    const s16x8 onesb = (s16x8)(short)0x3F80;  // bf16 1.0 splat (l-sum B)

    s16x8 aqL[2], aqH[2];
#pragma unroll
    for (int kk = 0; kk < 2; ++kk) {
        aqL[kk] = *reinterpret_cast<const s16x8*>(
            &Qb[(size_t)(q0L + wid * 16 + l15) * 64 + kk * 32 + 8 * lhi]);
        aqH[kk] = *reinterpret_cast<const s16x8*>(
            &Qb[(size_t)(q0H + wid * 16 + l15) * 64 + kk * 32 + 8 * lhi]);
    }

    f32x4 oL[4], oH[4];
#pragma unroll
    for (int nb = 0; nb < 4; ++nb) { oL[nb] = (f32x4)0.f; oH[nb] = (f32x4)0.f; }
    f32x4 lL = (f32x4)0.f, lH = (f32x4)0.f;

    const unsigned short* kpt = Kb + (16 * wid + sub) * 64 + scol;
    const unsigned short* vpt = Vb + (size_t)(16 * wid + sub) * SLEN + scol;

    auto stageK = [&](int bsel) {
        char* kd = smem + bsel * 8192 + wid * 2048;
        gload_lds16(kpt,       kd);
        gload_lds16(kpt + 512, kd + 1024);
        kpt += 4096;
    };
    auto stageV = [&]() {
        char* vd = smem + 16384 + wid * 2048;
        gload_lds16(vpt,         vd);
        gload_lds16(vpt + 16384, vd + 1024);
        vpt += 64;
    };

    // QK^T + mask + exp2 + P-store (scores die here; P in LDS)
    auto qksm = [&](s16x8 (&aq)[2], bool domask, const char* c0, const char* c1) {
        f32x4 sc2[4];
        __builtin_amdgcn_s_setprio(1);
        {
            s16x8 ak[4];
#pragma unroll
            for (int nb = 0; nb < 4; ++nb)
                ak[nb] = *reinterpret_cast<const s16x8*>(c0 + nb * 2048);
#pragma unroll
            for (int nb = 0; nb < 4; ++nb)
                sc2[nb] = __builtin_amdgcn_mfma_f32_16x16x32_bf16(ak[nb], aq[0], fzero, 0, 0, 0);
#pragma unroll
            for (int nb = 0; nb < 4; ++nb)
                ak[nb] = *reinterpret_cast<const s16x8*>(c1 + nb * 2048);
#pragma unroll
            for (int nb = 0; nb < 4; ++nb)
                sc2[nb] = __builtin_amdgcn_mfma_f32_16x16x32_bf16(ak[nb], aq[1], sc2[nb], 0, 0, 0);
        }
        __builtin_amdgcn_s_setprio(0);

        if (domask) {
#pragma unroll
            for (int nb = 0; nb < 4; ++nb)
#pragma unroll
                for (int r = 0; r < 4; ++r)
                    if (nb * 16 + lhi * 4 + r > thr) sc2[nb][r] = -1e30f;
        }
#pragma unroll
        for (int nb = 0; nb < 4; ++nb) {
            float p0 = exp2f(sc2[nb][0]);
            float p1 = exp2f(sc2[nb][1]);
            float p2 = exp2f(sc2[nb][2]);
            float p3 = exp2f(sc2[nb][3]);
            uint2 u;
            u.x = cvtpk(p0, p1);
            u.y = cvtpk(p2, p3);
            *reinterpret_cast<uint2*>(PWp + pw[nb]) = u;
        }
    };

    // PV from P (own wave) and the single V buffer
    auto pv = [&](f32x4 (&o_acc)[4], f32x4& l_acc) {
        __builtin_amdgcn_s_setprio(1);
#pragma unroll
        for (int kk = 0; kk < 2; ++kk) {
            s16x8 pa = *reinterpret_cast<const s16x8*>(kk ? pb1 : pb0);
            const char* vb = kk ? vr1 : vr0;
            s16x8 bvv[4];
#pragma unroll
            for (int nb = 0; nb < 4; ++nb)
                bvv[nb] = *reinterpret_cast<const s16x8*>(vb + nb * 2048);
#pragma unroll
            for (int nb = 0; nb < 4; ++nb)
                o_acc[nb] = __builtin_amdgcn_mfma_f32_16x16x32_bf16(pa, bvv[nb], o_acc[nb], 0, 0, 0);
            l_acc = __builtin_amdgcn_mfma_f32_16x16x32_bf16(pa, onesb, l_acc, 0, 0, 0);
        }
        __builtin_amdgcn_s_setprio(0);
    };

    // prologue: K(0) into buf0
    stageK(0);
    asm volatile("s_waitcnt vmcnt(0)" ::: "memory");
    __builtin_amdgcn_s_barrier();
    __builtin_amdgcn_sched_barrier(0);

    int cur = 0;
    const int nt = qtH + 1;

#pragma unroll 1
    for (int t = 0; t < nt; ++t) {
        stageV();                              // V(t): oldest vmem this round
        const bool pk = (t + 1 < nt);
        if (pk) stageK(cur ^ 1);               // K(t+1): stays in flight
        const char* c0 = smem + cur * 8192 + kb0;
        const char* c1 = smem + cur * 8192 + kb1;

        if (t <= qtL) {
            qksm(aqL, t == qtL, c0, c1);
            if (pk) asm volatile("s_waitcnt vmcnt(2)" ::: "memory");
            else    asm volatile("s_waitcnt vmcnt(0)" ::: "memory");
            __builtin_amdgcn_s_barrier();      // V visible to all waves
            __builtin_amdgcn_sched_barrier(0);
            pv(oL, lL);
            qksm(aqH, false, c0, c1);          // t <= qtL < qtH: never masked
            pv(oH, lH);
        } else {
            qksm(aqH, t == qtH, c0, c1);
            if (pk) asm volatile("s_waitcnt vmcnt(2)" ::: "memory");
            else    asm volatile("s_waitcnt vmcnt(0)" ::: "memory");
            __builtin_amdgcn_s_barrier();
            __builtin_amdgcn_sched_barrier(0);
            pv(oH, lH);
        }

        // end of round: drain K prefetch (had a full round in flight), all
        // LDS reads retired -> safe to overwrite K[cur] and V next round.
        asm volatile("s_waitcnt vmcnt(0) lgkmcnt(0)" ::: "memory");
        __builtin_amdgcn_s_barrier();
        __builtin_amdgcn_sched_barrier(0);
        cur ^= 1;
    }

    float liL[4], liH[4];
#pragma unroll
    for (int r = 0; r < 4; ++r) { liL[r] = 1.0f / lL[r]; liH[r] = 1.0f / lH[r]; }
#pragma unroll
    for (int nb = 0; nb < 4; ++nb)
#pragma unroll
        for (int r = 0; r < 4; ++r) {
            const int sL = q0L + wid * 16 + lhi * 4 + r;
            const int sH = q0H + wid * 16 + lhi * 4 + r;
            const size_t cix = h * 64 + nb * 16 + l15;
            Ao[((size_t)b * SLEN + sL) * DMOD + cix] = f2bf(oL[nb][r] * liL[r]);
            Ao[((size_t)b * SLEN + sH) * DMOD + cix] = f2bf(oH[nb][r] * liH[r]);
        }
}

extern "C" void kernel_launch(void* const* d_in, const int* in_sizes, int n_in,
                              void* d_out, int out_size, void* d_ws, size_t ws_size,
                              hipStream_t stream) {
    const float* q  = (const float*)d_in[0];
    const float* k  = (const float*)d_in[1];
    const float* v  = (const float*)d_in[2];
    const float* Wq = (const float*)d_in[4];
    const float* bq = (const float*)d_in[5];
    const float* Wk = (const float*)d_in[6];
    const float* bk = (const float*)d_in[7];
    const float* Wv = (const float*)d_in[8];
    const float* bv = (const float*)d_in[9];
    const float* Wo = (const float*)d_in[10];
    const float* bo = (const float*)d_in[11];

    // ws layout (ushort units): 4 bf16 W's + Q + K + V^T + attn-out = 75 MB.
    unsigned short* wsp = (unsigned short*)d_ws;
    unsigned short* wqc = wsp;
    unsigned short* wkc = wsp + 1048576;
    unsigned short* wvc = wsp + 2097152;
    unsigned short* woc = wsp + 3145728;
    unsigned short* qb  = wsp + 4194304;
    unsigned short* kb  = wsp + 12582912;
    unsigned short* vtb = wsp + 20971520;
    unsigned short* ao  = wsp + 29360128;

    dim3 gb(256);
    convert_w<<<dim3(512), gb, 0, stream>>>(Wq, Wk, Wv, Wo, wsp);
    gemm_qkv<0><<<dim3(512), gb, 0, stream>>>(q, wqc, bq, qb, EXPC);   // Q pre-scaled
    gemm_qkv<0><<<dim3(512), gb, 0, stream>>>(k, wkc, bk, kb, 1.0f);
    gemm_qkv<1><<<dim3(512), gb, 0, stream>>>(v, wvc, bv, vtb, 1.0f);
    attn_kernel<<<dim3(1024), gb, 0, stream>>>(qb, kb, vtb, ao);
    gemm_out<<<dim3(512), gb, 0, stream>>>(ao, woc, bo, (float*)d_out);
}

// Round 21
// 257.946 us; speedup vs baseline: 1.8840x; 1.8840x over previous
//
#include <hip/hip_runtime.h>
#include <hip/hip_bf16.h>

// B=4, S=2048, D=1024, H=16, HD=64, causal MHA forward, fp32 in/out.
// Pipeline: convert-W -> 3 QKV GEMMs (fp32 A, 2-deep reg prefetch, counted
// vmcnt barriers) -> flash attn v14b (single-V, 5 blocks/CU via LDS, default
// 128-VGPR budget) -> out GEMM.

#define SLEN 2048
#define DMOD 1024

typedef __attribute__((ext_vector_type(8))) short s16x8;   // 8 bf16 (4 VGPRs)
typedef __attribute__((ext_vector_type(4))) float f32x4;

__device__ __forceinline__ unsigned short f2bf(float f) {
    union { __hip_bfloat16 h; unsigned short u; } cv;
    cv.h = __float2bfloat16(f);
    return cv.u;
}
__device__ __forceinline__ unsigned cvtpk(float a, float b) {
    unsigned r;
    asm("v_cvt_pk_bf16_f32 %0, %1, %2" : "=v"(r) : "v"(a), "v"(b));
    return r;
}
__device__ __forceinline__ void gload_lds16(const void* g, void* l) {
    __builtin_amdgcn_global_load_lds(
        (const __attribute__((address_space(1))) void*)g,
        (__attribute__((address_space(3))) void*)l, 16, 0, 0);
}

// ---------------- fp32 -> bf16 convert (weights only) --------------------
__global__ __launch_bounds__(256) void convert_w(
    const float* __restrict__ wq, const float* __restrict__ wk,
    const float* __restrict__ wv, const float* __restrict__ wo,
    unsigned short* __restrict__ dst)
{
    const int bid = blockIdx.x, tid = threadIdx.x;
    const int w = bid >> 7;
    const float* src = (w == 0) ? wq : (w == 1) ? wk : (w == 2) ? wv : wo;
    unsigned short* d = dst + (size_t)w * 1048576;
    const size_t off = (size_t)(bid & 127) * 8192;
#pragma unroll
    for (int i = 0; i < 8; ++i) {
        const size_t e = off + (size_t)(i * 256 + tid) * 4;
        float4 x = *reinterpret_cast<const float4*>(&src[e]);
        uint2 u;
        u.x = cvtpk(x.x, x.y);
        u.y = cvtpk(x.z, x.w);
        *reinterpret_cast<uint2*>(&d[e]) = u;
    }
}

// ---------------- QKV GEMM v3 (round-16 proven): 2-deep A prefetch -------
template<int MODE>
__global__ __launch_bounds__(256, 2) void gemm_qkv(
    const float* __restrict__ A, const unsigned short* __restrict__ W,
    const float* __restrict__ bias, unsigned short* __restrict__ outp,
    float oscale)
{
    __shared__ unsigned short Asm[2][8192];
    __shared__ unsigned short Bsm[2][8192];

    const int tid  = threadIdx.x;
    const int lane = tid & 63, wid = tid >> 6;
    const int l15 = lane & 15, lhi = lane >> 4;

    const int flat = blockIdx.x;
    const int logical = (flat & 7) * 64 + (flat >> 3);
    const int m0 = (logical >> 3) * 128, n0 = (logical & 7) * 128;
    const int wr = wid >> 1, wc = wid & 1;

    int soff[4];
    const float* aptc[4];
#pragma unroll
    for (int i = 0; i < 4; ++i) {
        const int f = i * 256 + tid;
        const int srow = f >> 3, sg = f & 7;
        soff[i] = srow * 128 + ((sg ^ (srow & 7)) * 16);
        aptc[i] = A + (size_t)(m0 + srow) * 1024 + sg * 8;
    }
    const int wsrow = lane >> 3;
    const int wsgr  = (lane & 7) ^ wsrow;
    const unsigned short* bpt = W + (size_t)(n0 + wid * 8 + wsrow) * 1024 + wsgr * 8;

    int aoff[2][4], boff[2][4];
#pragma unroll
    for (int kk = 0; kk < 2; ++kk)
#pragma unroll
        for (int i = 0; i < 4; ++i) {
            const int s = ((4 * kk + lhi) ^ (l15 & 7)) * 16;
            aoff[kk][i] = (wr * 64 + i * 16 + l15) * 128 + s;
            boff[kk][i] = (wc * 64 + i * 16 + l15) * 128 + s;
        }

    f32x4 acc[4][4];
#pragma unroll
    for (int i = 0; i < 4; ++i)
#pragma unroll
        for (int j = 0; j < 4; ++j) acc[i][j] = (f32x4)0.f;

    float4 awE[8], awO[8];

    auto loadTo = [&](float4 (&aw)[8], int k0) {
#pragma unroll
        for (int i = 0; i < 4; ++i) {
            aw[2 * i]     = *reinterpret_cast<const float4*>(aptc[i] + k0);
            aw[2 * i + 1] = *reinterpret_cast<const float4*>(aptc[i] + k0 + 4);
        }
    };
    auto writeFrom = [&](float4 (&aw)[8], int bsel) {
#pragma unroll
        for (int i = 0; i < 4; ++i) {
            uint4 u;
            u.x = cvtpk(aw[2 * i].x,     aw[2 * i].y);
            u.y = cvtpk(aw[2 * i].z,     aw[2 * i].w);
            u.z = cvtpk(aw[2 * i + 1].x, aw[2 * i + 1].y);
            u.w = cvtpk(aw[2 * i + 1].z, aw[2 * i + 1].w);
            *reinterpret_cast<uint4*>((char*)&Asm[bsel][0] + soff[i]) = u;
        }
    };
    auto stageW = [&](int bsel) {
        char* bd = (char*)Bsm + bsel * 16384 + wid * 1024;
#pragma unroll
        for (int i = 0; i < 4; ++i)
            gload_lds16(bpt + i * 32768, bd + i * 4096);
        bpt += 64;
    };
    auto mfmaPhase = [&](const char* AB, const char* BB) {
#pragma unroll
        for (int kk = 0; kk < 2; ++kk) {
            s16x8 af[4], bfv[4];
#pragma unroll
            for (int i = 0; i < 4; ++i) af[i]  = *reinterpret_cast<const s16x8*>(AB + aoff[kk][i]);
#pragma unroll
            for (int j = 0; j < 4; ++j) bfv[j] = *reinterpret_cast<const s16x8*>(BB + boff[kk][j]);
#pragma unroll
            for (int i = 0; i < 4; ++i)
#pragma unroll
                for (int j = 0; j < 4; ++j)
                    acc[i][j] = __builtin_amdgcn_mfma_f32_16x16x32_bf16(af[i], bfv[j], acc[i][j], 0, 0, 0);
        }
    };
    auto barrier8 = [&]() {
        asm volatile("s_waitcnt vmcnt(8) lgkmcnt(0)" ::: "memory");
        __builtin_amdgcn_s_barrier();
        __builtin_amdgcn_sched_barrier(0);
    };
    auto barrier0 = [&]() {
        asm volatile("s_waitcnt vmcnt(0) lgkmcnt(0)" ::: "memory");
        __builtin_amdgcn_s_barrier();
        __builtin_amdgcn_sched_barrier(0);
    };

    loadTo(awE, 0);
    stageW(0);
    writeFrom(awE, 0);
    loadTo(awO, 64);
    barrier8();

#pragma unroll 1
    for (int kt = 0; kt < 16; kt += 2) {
        if (kt + 1 < 16) stageW(1);
        if (kt + 2 < 16) loadTo(awE, (kt + 2) * 64);
        mfmaPhase((const char*)&Asm[0][0], (const char*)&Bsm[0][0]);
        if (kt + 1 < 16) writeFrom(awO, 1);
        if (kt + 2 < 16) barrier8(); else barrier0();
        if (kt + 2 < 16) stageW(0);
        if (kt + 3 < 16) loadTo(awO, (kt + 3) * 64);
        mfmaPhase((const char*)&Asm[1][0], (const char*)&Bsm[1][0]);
        if (kt + 2 < 16) writeFrom(awE, 0);
        if (kt + 3 < 16) barrier8(); else barrier0();
    }

#pragma unroll
    for (int j = 0; j < 4; ++j) {
        const int col = n0 + wc * 64 + j * 16 + l15;
        const float bv = bias[col];
#pragma unroll
        for (int i = 0; i < 4; ++i) {
#pragma unroll
            for (int r = 0; r < 4; ++r) {
                const int row = m0 + wr * 64 + i * 16 + lhi * 4 + r;
                const float val = (acc[i][j][r] + bv) * oscale;
                if constexpr (MODE == 0) {
                    outp[(size_t)((row >> 11) * 16 + (col >> 6)) * 131072
                         + (size_t)(row & 2047) * 64 + (col & 63)] = f2bf(val);
                } else {
                    outp[(size_t)((row >> 11) * 16 + (col >> 6)) * 131072
                         + (size_t)(col & 63) * 2048 + (row & 2047)] = f2bf(val);
                }
            }
        }
    }
}

// ---------------- out-proj GEMM (bf16 A via DMA, fp32 out) ---------------
__global__ __launch_bounds__(256) void gemm_out(
    const unsigned short* __restrict__ A, const unsigned short* __restrict__ W,
    const float* __restrict__ bias, float* __restrict__ outp)
{
    __shared__ unsigned short Asm[2][8192];
    __shared__ unsigned short Bsm[2][8192];

    const int tid  = threadIdx.x;
    const int lane = tid & 63, wid = tid >> 6;
    const int l15 = lane & 15, lhi = lane >> 4;

    const int flat = blockIdx.x;
    const int logical = (flat & 7) * 64 + (flat >> 3);
    const int m0 = (logical >> 3) * 128, n0 = (logical & 7) * 128;

    const int wr = wid >> 1, wc = wid & 1;
    const int srow = lane >> 3;
    const int sgr  = (lane & 7) ^ srow;

    int aoff[2][4], boff[2][4];
#pragma unroll
    for (int kk = 0; kk < 2; ++kk)
#pragma unroll
        for (int i = 0; i < 4; ++i) {
            const int s = ((4 * kk + lhi) ^ (l15 & 7)) * 16;
            aoff[kk][i] = (wr * 64 + i * 16 + l15) * 128 + s;
            boff[kk][i] = (wc * 64 + i * 16 + l15) * 128 + s;
        }

    const unsigned short* apt = A + (size_t)(m0 + wid * 8 + srow) * 1024 + sgr * 8;
    const unsigned short* bpt = W + (size_t)(n0 + wid * 8 + srow) * 1024 + sgr * 8;

    f32x4 acc[4][4];
#pragma unroll
    for (int i = 0; i < 4; ++i)
#pragma unroll
        for (int j = 0; j < 4; ++j) acc[i][j] = (f32x4)0.f;

    auto stage = [&](int bsel) {
        char* ad = (char*)Asm + bsel * 16384 + wid * 1024;
        char* bd = (char*)Bsm + bsel * 16384 + wid * 1024;
#pragma unroll
        for (int i = 0; i < 4; ++i) {
            gload_lds16(apt + i * 32768, ad + i * 4096);
            gload_lds16(bpt + i * 32768, bd + i * 4096);
        }
        apt += 64; bpt += 64;
    };

    stage(0);
    __syncthreads();
    int cur = 0;
#pragma unroll 1
    for (int kt = 0; kt < 16; ++kt) {
        if (kt < 15) stage(cur ^ 1);
        const char* AB = (const char*)Asm + cur * 16384;
        const char* BB = (const char*)Bsm + cur * 16384;
#pragma unroll
        for (int kk = 0; kk < 2; ++kk) {
            s16x8 af[4], bfv[4];
#pragma unroll
            for (int i = 0; i < 4; ++i) af[i]  = *reinterpret_cast<const s16x8*>(AB + aoff[kk][i]);
#pragma unroll
            for (int j = 0; j < 4; ++j) bfv[j] = *reinterpret_cast<const s16x8*>(BB + boff[kk][j]);
#pragma unroll
            for (int i = 0; i < 4; ++i)
#pragma unroll
                for (int j = 0; j < 4; ++j)
                    acc[i][j] = __builtin_amdgcn_mfma_f32_16x16x32_bf16(af[i], bfv[j], acc[i][j], 0, 0, 0);
        }
        __syncthreads();
        cur ^= 1;
    }

#pragma unroll
    for (int j = 0; j < 4; ++j) {
        const int col = n0 + wc * 64 + j * 16 + l15;
        const float bv = bias[col];
#pragma unroll
        for (int i = 0; i < 4; ++i)
#pragma unroll
            for (int r = 0; r < 4; ++r) {
                const int row = m0 + wr * 64 + i * 16 + lhi * 4 + r;
                outp[(size_t)row * 1024 + col] = acc[i][j][r] + bv;
            }
    }
}

// ---------------- flash attention v14b -----------------------------------
// Single V buffer: LDS 32768 -> 5 blocks/CU (LDS-limited; VGPR ~56 is not
// the limiter). Default-ish launch bound (256,4) keeps the 128-VGPR budget
// (round-20 lesson: (256,5) strangled the allocator into scratch spills).
// Per round: V(t) DMA, K(t+1) DMA; QK+softmax; vmcnt(2)+barrier (V ready,
// K pair stays in flight); PV; full-drain barrier.
#define EXPC 0.18033688011112043f   // 0.125 * log2(e)

__global__ __launch_bounds__(256, 4) void attn_kernel(
    const unsigned short* __restrict__ Q,
    const unsigned short* __restrict__ Kc,
    const unsigned short* __restrict__ Vt,
    unsigned short* __restrict__ Ao)
{
    // [0,16K): K dbuf (8K each)  [16K,24K): V single  [24K,32K): per-wave P
    __shared__ char smem[32768];

    const int tid = threadIdx.x, lane = tid & 63, wid = tid >> 6;
    const int l15 = lane & 15, lhi = lane >> 4;
    const int sK = l15 & 7;
    const int sub = lane >> 3, c8s = lane & 7;
    const int thr = wid * 16 + l15;

    const int kb0 = l15 * 128 + (lhi ^ sK) * 16;
    const int kb1 = kb0 ^ 64;
    char* const pb0 = smem + 24576 + wid * 2048 + kb0;
    char* const pb1 = smem + 24576 + wid * 2048 + kb1;
    char* const PWp = smem + 24576 + wid * 2048;
    const char* const vr0 = smem + 16384 + kb0;   // V read bases (fixed)
    const char* const vr1 = smem + 16384 + kb1;
    int pw[4];
#pragma unroll
    for (int nb = 0; nb < 4; ++nb)
        pw[nb] = (l15 * 16 + ((nb * 4 + lhi) ^ (2 * sK))) * 8;

    const int flat = blockIdx.x;
    const int logical = (flat & 7) * 128 + (flat >> 3);
    const int bx = logical & 15, bh = logical >> 4;
    const int qtL = bx, qtH = 31 - bx;
    const int q0L = qtL * 64, q0H = qtH * 64;

    const size_t base = (size_t)bh * SLEN * 64;
    const unsigned short* Qb = Q + base;
    const unsigned short* Kb = Kc + base;
    const unsigned short* Vb = Vt + base;      // [64][SLEN]
    const int b = bh >> 4, h = bh & 15;
    const int scol = (c8s ^ sub) * 8;

    const f32x4 fzero = (f32x4)0.f;
    const s16x8 onesb = (s16x8)(short)0x3F80;  // bf16 1.0 splat (l-sum B)

    s16x8 aqL[2], aqH[2];
#pragma unroll
    for (int kk = 0; kk < 2; ++kk) {
        aqL[kk] = *reinterpret_cast<const s16x8*>(
            &Qb[(size_t)(q0L + wid * 16 + l15) * 64 + kk * 32 + 8 * lhi]);
        aqH[kk] = *reinterpret_cast<const s16x8*>(
            &Qb[(size_t)(q0H + wid * 16 + l15) * 64 + kk * 32 + 8 * lhi]);
    }

    f32x4 oL[4], oH[4];
#pragma unroll
    for (int nb = 0; nb < 4; ++nb) { oL[nb] = (f32x4)0.f; oH[nb] = (f32x4)0.f; }
    f32x4 lL = (f32x4)0.f, lH = (f32x4)0.f;

    const unsigned short* kpt = Kb + (16 * wid + sub) * 64 + scol;
    const unsigned short* vpt = Vb + (size_t)(16 * wid + sub) * SLEN + scol;

    auto stageK = [&](int bsel) {
        char* kd = smem + bsel * 8192 + wid * 2048;
        gload_lds16(kpt,       kd);
        gload_lds16(kpt + 512, kd + 1024);
        kpt += 4096;
    };
    auto stageV = [&]() {
        char* vd = smem + 16384 + wid * 2048;
        gload_lds16(vpt,         vd);
        gload_lds16(vpt + 16384, vd + 1024);
        vpt += 64;
    };

    // QK^T + mask + exp2 + P-store (scores die here; P in LDS)
    auto qksm = [&](s16x8 (&aq)[2], bool domask, const char* c0, const char* c1) {
        f32x4 sc2[4];
        __builtin_amdgcn_s_setprio(1);
        {
            s16x8 ak[4];
#pragma unroll
            for (int nb = 0; nb < 4; ++nb)
                ak[nb] = *reinterpret_cast<const s16x8*>(c0 + nb * 2048);
#pragma unroll
            for (int nb = 0; nb < 4; ++nb)
                sc2[nb] = __builtin_amdgcn_mfma_f32_16x16x32_bf16(ak[nb], aq[0], fzero, 0, 0, 0);
#pragma unroll
            for (int nb = 0; nb < 4; ++nb)
                ak[nb] = *reinterpret_cast<const s16x8*>(c1 + nb * 2048);
#pragma unroll
            for (int nb = 0; nb < 4; ++nb)
                sc2[nb] = __builtin_amdgcn_mfma_f32_16x16x32_bf16(ak[nb], aq[1], sc2[nb], 0, 0, 0);
        }
        __builtin_amdgcn_s_setprio(0);

        if (domask) {
#pragma unroll
            for (int nb = 0; nb < 4; ++nb)
#pragma unroll
                for (int r = 0; r < 4; ++r)
                    if (nb * 16 + lhi * 4 + r > thr) sc2[nb][r] = -1e30f;
        }
#pragma unroll
        for (int nb = 0; nb < 4; ++nb) {
            float p0 = exp2f(sc2[nb][0]);
            float p1 = exp2f(sc2[nb][1]);
            float p2 = exp2f(sc2[nb][2]);
            float p3 = exp2f(sc2[nb][3]);
            uint2 u;
            u.x = cvtpk(p0, p1);
            u.y = cvtpk(p2, p3);
            *reinterpret_cast<uint2*>(PWp + pw[nb]) = u;
        }
    };

    // PV from P (own wave) and the single V buffer
    auto pv = [&](f32x4 (&o_acc)[4], f32x4& l_acc) {
        __builtin_amdgcn_s_setprio(1);
#pragma unroll
        for (int kk = 0; kk < 2; ++kk) {
            s16x8 pa = *reinterpret_cast<const s16x8*>(kk ? pb1 : pb0);
            const char* vb = kk ? vr1 : vr0;
            s16x8 bvv[4];
#pragma unroll
            for (int nb = 0; nb < 4; ++nb)
                bvv[nb] = *reinterpret_cast<const s16x8*>(vb + nb * 2048);
#pragma unroll
            for (int nb = 0; nb < 4; ++nb)
                o_acc[nb] = __builtin_amdgcn_mfma_f32_16x16x32_bf16(pa, bvv[nb], o_acc[nb], 0, 0, 0);
            l_acc = __builtin_amdgcn_mfma_f32_16x16x32_bf16(pa, onesb, l_acc, 0, 0, 0);
        }
        __builtin_amdgcn_s_setprio(0);
    };

    // prologue: K(0) into buf0
    stageK(0);
    asm volatile("s_waitcnt vmcnt(0)" ::: "memory");
    __builtin_amdgcn_s_barrier();
    __builtin_amdgcn_sched_barrier(0);

    int cur = 0;
    const int nt = qtH + 1;

#pragma unroll 1
    for (int t = 0; t < nt; ++t) {
        stageV();                              // V(t): oldest vmem this round
        const bool pk = (t + 1 < nt);
        if (pk) stageK(cur ^ 1);               // K(t+1): stays in flight
        const char* c0 = smem + cur * 8192 + kb0;
        const char* c1 = smem + cur * 8192 + kb1;

        if (t <= qtL) {
            qksm(aqL, t == qtL, c0, c1);
            if (pk) asm volatile("s_waitcnt vmcnt(2)" ::: "memory");
            else    asm volatile("s_waitcnt vmcnt(0)" ::: "memory");
            __builtin_amdgcn_s_barrier();      // V visible to all waves
            __builtin_amdgcn_sched_barrier(0);
            pv(oL, lL);
            qksm(aqH, false, c0, c1);          // t <= qtL < qtH: never masked
            pv(oH, lH);
        } else {
            qksm(aqH, t == qtH, c0, c1);
            if (pk) asm volatile("s_waitcnt vmcnt(2)" ::: "memory");
            else    asm volatile("s_waitcnt vmcnt(0)" ::: "memory");
            __builtin_amdgcn_s_barrier();
            __builtin_amdgcn_sched_barrier(0);
            pv(oH, lH);
        }

        // end of round: drain K prefetch, all LDS reads retired.
        asm volatile("s_waitcnt vmcnt(0) lgkmcnt(0)" ::: "memory");
        __builtin_amdgcn_s_barrier();
        __builtin_amdgcn_sched_barrier(0);
        cur ^= 1;
    }

    float liL[4], liH[4];
#pragma unroll
    for (int r = 0; r < 4; ++r) { liL[r] = 1.0f / lL[r]; liH[r] = 1.0f / lH[r]; }
#pragma unroll
    for (int nb = 0; nb < 4; ++nb)
#pragma unroll
        for (int r = 0; r < 4; ++r) {
            const int sL = q0L + wid * 16 + lhi * 4 + r;
            const int sH = q0H + wid * 16 + lhi * 4 + r;
            const size_t cix = h * 64 + nb * 16 + l15;
            Ao[((size_t)b * SLEN + sL) * DMOD + cix] = f2bf(oL[nb][r] * liL[r]);
            Ao[((size_t)b * SLEN + sH) * DMOD + cix] = f2bf(oH[nb][r] * liH[r]);
        }
}

extern "C" void kernel_launch(void* const* d_in, const int* in_sizes, int n_in,
                              void* d_out, int out_size, void* d_ws, size_t ws_size,
                              hipStream_t stream) {
    const float* q  = (const float*)d_in[0];
    const float* k  = (const float*)d_in[1];
    const float* v  = (const float*)d_in[2];
    const float* Wq = (const float*)d_in[4];
    const float* bq = (const float*)d_in[5];
    const float* Wk = (const float*)d_in[6];
    const float* bk = (const float*)d_in[7];
    const float* Wv = (const float*)d_in[8];
    const float* bv = (const float*)d_in[9];
    const float* Wo = (const float*)d_in[10];
    const float* bo = (const float*)d_in[11];

    // ws layout (ushort units): 4 bf16 W's + Q + K + V^T + attn-out = 75 MB.
    unsigned short* wsp = (unsigned short*)d_ws;
    unsigned short* wqc = wsp;
    unsigned short* wkc = wsp + 1048576;
    unsigned short* wvc = wsp + 2097152;
    unsigned short* woc = wsp + 3145728;
    unsigned short* qb  = wsp + 4194304;
    unsigned short* kb  = wsp + 12582912;
    unsigned short* vtb = wsp + 20971520;
    unsigned short* ao  = wsp + 29360128;

    dim3 gb(256);
    convert_w<<<dim3(512), gb, 0, stream>>>(Wq, Wk, Wv, Wo, wsp);
    gemm_qkv<0><<<dim3(512), gb, 0, stream>>>(q, wqc, bq, qb, EXPC);   // Q pre-scaled
    gemm_qkv<0><<<dim3(512), gb, 0, stream>>>(k, wkc, bk, kb, 1.0f);
    gemm_qkv<1><<<dim3(512), gb, 0, stream>>>(v, wvc, bv, vtb, 1.0f);
    attn_kernel<<<dim3(1024), gb, 0, stream>>>(qb, kb, vtb, ao);
    gemm_out<<<dim3(512), gb, 0, stream>>>(ao, woc, bo, (float*)d_out);
}

// Round 22
// 170.212 us; speedup vs baseline: 2.8551x; 1.5154x over previous
//
#include <hip/hip_runtime.h>
#include <hip/hip_bf16.h>

// B=4, S=2048, D=1024, H=16, HD=64, causal MHA forward, fp32 in/out.
// FINAL (round-16 best, 170.3us): convert-W -> 3 QKV GEMMs (fp32 A, 2-deep
// reg prefetch, counted vmcnt barriers) -> flash attn v10 -> out GEMM.

#define SLEN 2048
#define DMOD 1024

typedef __attribute__((ext_vector_type(8))) short s16x8;   // 8 bf16 (4 VGPRs)
typedef __attribute__((ext_vector_type(4))) float f32x4;

__device__ __forceinline__ unsigned short f2bf(float f) {
    union { __hip_bfloat16 h; unsigned short u; } cv;
    cv.h = __float2bfloat16(f);
    return cv.u;
}
__device__ __forceinline__ unsigned cvtpk(float a, float b) {
    unsigned r;
    asm("v_cvt_pk_bf16_f32 %0, %1, %2" : "=v"(r) : "v"(a), "v"(b));
    return r;
}
__device__ __forceinline__ void gload_lds16(const void* g, void* l) {
    __builtin_amdgcn_global_load_lds(
        (const __attribute__((address_space(1))) void*)g,
        (__attribute__((address_space(3))) void*)l, 16, 0, 0);
}

// ---------------- fp32 -> bf16 convert (weights only) --------------------
__global__ __launch_bounds__(256) void convert_w(
    const float* __restrict__ wq, const float* __restrict__ wk,
    const float* __restrict__ wv, const float* __restrict__ wo,
    unsigned short* __restrict__ dst)
{
    const int bid = blockIdx.x, tid = threadIdx.x;
    const int w = bid >> 7;
    const float* src = (w == 0) ? wq : (w == 1) ? wk : (w == 2) ? wv : wo;
    unsigned short* d = dst + (size_t)w * 1048576;
    const size_t off = (size_t)(bid & 127) * 8192;
#pragma unroll
    for (int i = 0; i < 8; ++i) {
        const size_t e = off + (size_t)(i * 256 + tid) * 4;
        float4 x = *reinterpret_cast<const float4*>(&src[e]);
        uint2 u;
        u.x = cvtpk(x.x, x.y);
        u.y = cvtpk(x.z, x.w);
        *reinterpret_cast<uint2*>(&d[e]) = u;
    }
}

// ---------------- QKV GEMM (round-16 proven): 2-deep A prefetch ----------
// Per K-step: stageW(t+1); loadA(t+2); MFMA(t); cvt+ds_write A(t+1);
// s_waitcnt vmcnt(8) lgkmcnt(0); s_barrier  (A-loads stay in flight).
template<int MODE>
__global__ __launch_bounds__(256, 2) void gemm_qkv(
    const float* __restrict__ A, const unsigned short* __restrict__ W,
    const float* __restrict__ bias, unsigned short* __restrict__ outp,
    float oscale)
{
    __shared__ unsigned short Asm[2][8192];
    __shared__ unsigned short Bsm[2][8192];

    const int tid  = threadIdx.x;
    const int lane = tid & 63, wid = tid >> 6;
    const int l15 = lane & 15, lhi = lane >> 4;

    const int flat = blockIdx.x;
    const int logical = (flat & 7) * 64 + (flat >> 3);
    const int m0 = (logical >> 3) * 128, n0 = (logical & 7) * 128;
    const int wr = wid >> 1, wc = wid & 1;

    int soff[4];
    const float* aptc[4];
#pragma unroll
    for (int i = 0; i < 4; ++i) {
        const int f = i * 256 + tid;
        const int srow = f >> 3, sg = f & 7;
        soff[i] = srow * 128 + ((sg ^ (srow & 7)) * 16);
        aptc[i] = A + (size_t)(m0 + srow) * 1024 + sg * 8;
    }
    const int wsrow = lane >> 3;
    const int wsgr  = (lane & 7) ^ wsrow;
    const unsigned short* bpt = W + (size_t)(n0 + wid * 8 + wsrow) * 1024 + wsgr * 8;

    int aoff[2][4], boff[2][4];
#pragma unroll
    for (int kk = 0; kk < 2; ++kk)
#pragma unroll
        for (int i = 0; i < 4; ++i) {
            const int s = ((4 * kk + lhi) ^ (l15 & 7)) * 16;
            aoff[kk][i] = (wr * 64 + i * 16 + l15) * 128 + s;
            boff[kk][i] = (wc * 64 + i * 16 + l15) * 128 + s;
        }

    f32x4 acc[4][4];
#pragma unroll
    for (int i = 0; i < 4; ++i)
#pragma unroll
        for (int j = 0; j < 4; ++j) acc[i][j] = (f32x4)0.f;

    float4 awE[8], awO[8];

    auto loadTo = [&](float4 (&aw)[8], int k0) {
#pragma unroll
        for (int i = 0; i < 4; ++i) {
            aw[2 * i]     = *reinterpret_cast<const float4*>(aptc[i] + k0);
            aw[2 * i + 1] = *reinterpret_cast<const float4*>(aptc[i] + k0 + 4);
        }
    };
    auto writeFrom = [&](float4 (&aw)[8], int bsel) {
#pragma unroll
        for (int i = 0; i < 4; ++i) {
            uint4 u;
            u.x = cvtpk(aw[2 * i].x,     aw[2 * i].y);
            u.y = cvtpk(aw[2 * i].z,     aw[2 * i].w);
            u.z = cvtpk(aw[2 * i + 1].x, aw[2 * i + 1].y);
            u.w = cvtpk(aw[2 * i + 1].z, aw[2 * i + 1].w);
            *reinterpret_cast<uint4*>((char*)&Asm[bsel][0] + soff[i]) = u;
        }
    };
    auto stageW = [&](int bsel) {
        char* bd = (char*)Bsm + bsel * 16384 + wid * 1024;
#pragma unroll
        for (int i = 0; i < 4; ++i)
            gload_lds16(bpt + i * 32768, bd + i * 4096);
        bpt += 64;
    };
    auto mfmaPhase = [&](const char* AB, const char* BB) {
#pragma unroll
        for (int kk = 0; kk < 2; ++kk) {
            s16x8 af[4], bfv[4];
#pragma unroll
            for (int i = 0; i < 4; ++i) af[i]  = *reinterpret_cast<const s16x8*>(AB + aoff[kk][i]);
#pragma unroll
            for (int j = 0; j < 4; ++j) bfv[j] = *reinterpret_cast<const s16x8*>(BB + boff[kk][j]);
#pragma unroll
            for (int i = 0; i < 4; ++i)
#pragma unroll
                for (int j = 0; j < 4; ++j)
                    acc[i][j] = __builtin_amdgcn_mfma_f32_16x16x32_bf16(af[i], bfv[j], acc[i][j], 0, 0, 0);
        }
    };
    auto barrier8 = [&]() {
        asm volatile("s_waitcnt vmcnt(8) lgkmcnt(0)" ::: "memory");
        __builtin_amdgcn_s_barrier();
        __builtin_amdgcn_sched_barrier(0);
    };
    auto barrier0 = [&]() {
        asm volatile("s_waitcnt vmcnt(0) lgkmcnt(0)" ::: "memory");
        __builtin_amdgcn_s_barrier();
        __builtin_amdgcn_sched_barrier(0);
    };

    loadTo(awE, 0);
    stageW(0);
    writeFrom(awE, 0);
    loadTo(awO, 64);
    barrier8();

#pragma unroll 1
    for (int kt = 0; kt < 16; kt += 2) {
        if (kt + 1 < 16) stageW(1);
        if (kt + 2 < 16) loadTo(awE, (kt + 2) * 64);
        mfmaPhase((const char*)&Asm[0][0], (const char*)&Bsm[0][0]);
        if (kt + 1 < 16) writeFrom(awO, 1);
        if (kt + 2 < 16) barrier8(); else barrier0();
        if (kt + 2 < 16) stageW(0);
        if (kt + 3 < 16) loadTo(awO, (kt + 3) * 64);
        mfmaPhase((const char*)&Asm[1][0], (const char*)&Bsm[1][0]);
        if (kt + 2 < 16) writeFrom(awE, 0);
        if (kt + 3 < 16) barrier8(); else barrier0();
    }

#pragma unroll
    for (int j = 0; j < 4; ++j) {
        const int col = n0 + wc * 64 + j * 16 + l15;
        const float bv = bias[col];
#pragma unroll
        for (int i = 0; i < 4; ++i) {
#pragma unroll
            for (int r = 0; r < 4; ++r) {
                const int row = m0 + wr * 64 + i * 16 + lhi * 4 + r;
                const float val = (acc[i][j][r] + bv) * oscale;
                if constexpr (MODE == 0) {
                    outp[(size_t)((row >> 11) * 16 + (col >> 6)) * 131072
                         + (size_t)(row & 2047) * 64 + (col & 63)] = f2bf(val);
                } else {
                    outp[(size_t)((row >> 11) * 16 + (col >> 6)) * 131072
                         + (size_t)(col & 63) * 2048 + (row & 2047)] = f2bf(val);
                }
            }
        }
    }
}

// ---------------- out-proj GEMM (bf16 A via DMA, fp32 out) ---------------
__global__ __launch_bounds__(256) void gemm_out(
    const unsigned short* __restrict__ A, const unsigned short* __restrict__ W,
    const float* __restrict__ bias, float* __restrict__ outp)
{
    __shared__ unsigned short Asm[2][8192];
    __shared__ unsigned short Bsm[2][8192];

    const int tid  = threadIdx.x;
    const int lane = tid & 63, wid = tid >> 6;
    const int l15 = lane & 15, lhi = lane >> 4;

    const int flat = blockIdx.x;
    const int logical = (flat & 7) * 64 + (flat >> 3);
    const int m0 = (logical >> 3) * 128, n0 = (logical & 7) * 128;

    const int wr = wid >> 1, wc = wid & 1;
    const int srow = lane >> 3;
    const int sgr  = (lane & 7) ^ srow;

    int aoff[2][4], boff[2][4];
#pragma unroll
    for (int kk = 0; kk < 2; ++kk)
#pragma unroll
        for (int i = 0; i < 4; ++i) {
            const int s = ((4 * kk + lhi) ^ (l15 & 7)) * 16;
            aoff[kk][i] = (wr * 64 + i * 16 + l15) * 128 + s;
            boff[kk][i] = (wc * 64 + i * 16 + l15) * 128 + s;
        }

    const unsigned short* apt = A + (size_t)(m0 + wid * 8 + srow) * 1024 + sgr * 8;
    const unsigned short* bpt = W + (size_t)(n0 + wid * 8 + srow) * 1024 + sgr * 8;

    f32x4 acc[4][4];
#pragma unroll
    for (int i = 0; i < 4; ++i)
#pragma unroll
        for (int j = 0; j < 4; ++j) acc[i][j] = (f32x4)0.f;

    auto stage = [&](int bsel) {
        char* ad = (char*)Asm + bsel * 16384 + wid * 1024;
        char* bd = (char*)Bsm + bsel * 16384 + wid * 1024;
#pragma unroll
        for (int i = 0; i < 4; ++i) {
            gload_lds16(apt + i * 32768, ad + i * 4096);
            gload_lds16(bpt + i * 32768, bd + i * 4096);
        }
        apt += 64; bpt += 64;
    };

    stage(0);
    __syncthreads();
    int cur = 0;
#pragma unroll 1
    for (int kt = 0; kt < 16; ++kt) {
        if (kt < 15) stage(cur ^ 1);
        const char* AB = (const char*)Asm + cur * 16384;
        const char* BB = (const char*)Bsm + cur * 16384;
#pragma unroll
        for (int kk = 0; kk < 2; ++kk) {
            s16x8 af[4], bfv[4];
#pragma unroll
            for (int i = 0; i < 4; ++i) af[i]  = *reinterpret_cast<const s16x8*>(AB + aoff[kk][i]);
#pragma unroll
            for (int j = 0; j < 4; ++j) bfv[j] = *reinterpret_cast<const s16x8*>(BB + boff[kk][j]);
#pragma unroll
            for (int i = 0; i < 4; ++i)
#pragma unroll
                for (int j = 0; j < 4; ++j)
                    acc[i][j] = __builtin_amdgcn_mfma_f32_16x16x32_bf16(af[i], bfv[j], acc[i][j], 0, 0, 0);
        }
        __syncthreads();
        cur ^= 1;
    }

#pragma unroll
    for (int j = 0; j < 4; ++j) {
        const int col = n0 + wc * 64 + j * 16 + l15;
        const float bv = bias[col];
#pragma unroll
        for (int i = 0; i < 4; ++i)
#pragma unroll
            for (int r = 0; r < 4; ++r) {
                const int row = m0 + wr * 64 + i * 16 + lhi * 4 + r;
                outp[(size_t)row * 1024 + col] = acc[i][j][r] + bv;
            }
    }
}

// ---------------- flash attention v10 (proven, 70.3us) -------------------
// 4 waves, 2 q-tiles/block {bx,31-bx} (causal balance), DMA-staged swizzled
// K/V dbuf, one __syncthreads per round, fixed-shift exp2 softmax (Q pre-
// scaled by EXPC at projection), l via ones-MFMA, zero-shuffle epilogue.
#define EXPC 0.18033688011112043f   // 0.125 * log2(e)

__global__ __launch_bounds__(256, 4) void attn_kernel(
    const unsigned short* __restrict__ Q,
    const unsigned short* __restrict__ Kc,
    const unsigned short* __restrict__ Vt,
    unsigned short* __restrict__ Ao)
{
    // [0,16K): K dbuf  [16K,32K): V^T dbuf  [32K,40K): per-wave P
    __shared__ char smem[40960];

    const int tid = threadIdx.x, lane = tid & 63, wid = tid >> 6;
    const int l15 = lane & 15, lhi = lane >> 4;
    const int sK = l15 & 7;
    const int sub = lane >> 3, c8s = lane & 7;
    const int thr = wid * 16 + l15;

    const int kb0 = l15 * 128 + (lhi ^ sK) * 16;
    const int kb1 = kb0 ^ 64;
    char* const pb0 = smem + 32768 + wid * 2048 + kb0;
    char* const pb1 = smem + 32768 + wid * 2048 + kb1;
    char* const PWp = smem + 32768 + wid * 2048;
    int pw[4];
#pragma unroll
    for (int nb = 0; nb < 4; ++nb)
        pw[nb] = (l15 * 16 + ((nb * 4 + lhi) ^ (2 * sK))) * 8;

    const int flat = blockIdx.x;
    const int logical = (flat & 7) * 128 + (flat >> 3);
    const int bx = logical & 15, bh = logical >> 4;
    const int qtL = bx, qtH = 31 - bx;
    const int q0L = qtL * 64, q0H = qtH * 64;

    const size_t base = (size_t)bh * SLEN * 64;
    const unsigned short* Qb = Q + base;
    const unsigned short* Kb = Kc + base;
    const unsigned short* Vb = Vt + base;      // [64][SLEN]
    const int b = bh >> 4, h = bh & 15;
    const int scol = (c8s ^ sub) * 8;

    const f32x4 fzero = (f32x4)0.f;
    const s16x8 onesb = (s16x8)(short)0x3F80;  // bf16 1.0 splat (l-sum B)

    s16x8 aqL[2], aqH[2];
#pragma unroll
    for (int kk = 0; kk < 2; ++kk) {
        aqL[kk] = *reinterpret_cast<const s16x8*>(
            &Qb[(size_t)(q0L + wid * 16 + l15) * 64 + kk * 32 + 8 * lhi]);
        aqH[kk] = *reinterpret_cast<const s16x8*>(
            &Qb[(size_t)(q0H + wid * 16 + l15) * 64 + kk * 32 + 8 * lhi]);
    }

    f32x4 oL[4], oH[4];
#pragma unroll
    for (int nb = 0; nb < 4; ++nb) { oL[nb] = (f32x4)0.f; oH[nb] = (f32x4)0.f; }
    f32x4 lL = (f32x4)0.f, lH = (f32x4)0.f;

    const unsigned short* kpt = Kb + (16 * wid + sub) * 64 + scol;
    const unsigned short* vpt = Vb + (size_t)(16 * wid + sub) * SLEN + scol;

    auto stage = [&](int bsel) {
        char* kd = smem + bsel * 8192 + wid * 2048;
        char* vd = smem + 16384 + bsel * 8192 + wid * 2048;
        gload_lds16(kpt,         kd);
        gload_lds16(kpt + 512,   kd + 1024);
        gload_lds16(vpt,         vd);
        gload_lds16(vpt + 16384, vd + 1024);
        kpt += 4096; vpt += 64;
    };

    auto tile = [&](s16x8 (&aq)[2], f32x4 (&o_acc)[4], f32x4& l_acc,
                    bool domask, const char* c0, const char* c1) {
        f32x4 sc2[4];
        __builtin_amdgcn_s_setprio(1);
        {
            s16x8 ak[4];
#pragma unroll
            for (int nb = 0; nb < 4; ++nb)
                ak[nb] = *reinterpret_cast<const s16x8*>(c0 + nb * 2048);
#pragma unroll
            for (int nb = 0; nb < 4; ++nb)
                sc2[nb] = __builtin_amdgcn_mfma_f32_16x16x32_bf16(ak[nb], aq[0], fzero, 0, 0, 0);
#pragma unroll
            for (int nb = 0; nb < 4; ++nb)
                ak[nb] = *reinterpret_cast<const s16x8*>(c1 + nb * 2048);
#pragma unroll
            for (int nb = 0; nb < 4; ++nb)
                sc2[nb] = __builtin_amdgcn_mfma_f32_16x16x32_bf16(ak[nb], aq[1], sc2[nb], 0, 0, 0);
        }
        __builtin_amdgcn_s_setprio(0);

        if (domask) {
#pragma unroll
            for (int nb = 0; nb < 4; ++nb)
#pragma unroll
                for (int r = 0; r < 4; ++r)
                    if (nb * 16 + lhi * 4 + r > thr) sc2[nb][r] = -1e30f;
        }

#pragma unroll
        for (int nb = 0; nb < 4; ++nb) {
            float p0 = exp2f(sc2[nb][0]);
            float p1 = exp2f(sc2[nb][1]);
            float p2 = exp2f(sc2[nb][2]);
            float p3 = exp2f(sc2[nb][3]);
            uint2 u;
            u.x = cvtpk(p0, p1);
            u.y = cvtpk(p2, p3);
            *reinterpret_cast<uint2*>(PWp + pw[nb]) = u;
        }

        __builtin_amdgcn_s_setprio(1);
#pragma unroll
        for (int kk = 0; kk < 2; ++kk) {
            s16x8 pa = *reinterpret_cast<const s16x8*>(kk ? pb1 : pb0);
            const char* vb = (kk ? c1 : c0) + 16384;
            s16x8 bvv[4];
#pragma unroll
            for (int nb = 0; nb < 4; ++nb)
                bvv[nb] = *reinterpret_cast<const s16x8*>(vb + nb * 2048);
#pragma unroll
            for (int nb = 0; nb < 4; ++nb)
                o_acc[nb] = __builtin_amdgcn_mfma_f32_16x16x32_bf16(pa, bvv[nb], o_acc[nb], 0, 0, 0);
            l_acc = __builtin_amdgcn_mfma_f32_16x16x32_bf16(pa, onesb, l_acc, 0, 0, 0);
        }
        __builtin_amdgcn_s_setprio(0);
    };

    stage(0);
    __syncthreads();
    int cur = 0;
    const int nt = qtH + 1;

#pragma unroll 1
    for (int t = 0; t < nt; ++t) {
        if (t + 1 < nt) stage(cur ^ 1);
        const char* c0 = smem + cur * 8192 + kb0;
        const char* c1 = smem + cur * 8192 + kb1;
        if (t <= qtL) tile(aqL, oL, lL, t == qtL, c0, c1);
        tile(aqH, oH, lH, t == qtH, c0, c1);
        __syncthreads();
        cur ^= 1;
    }

    float liL[4], liH[4];
#pragma unroll
    for (int r = 0; r < 4; ++r) { liL[r] = 1.0f / lL[r]; liH[r] = 1.0f / lH[r]; }
#pragma unroll
    for (int nb = 0; nb < 4; ++nb)
#pragma unroll
        for (int r = 0; r < 4; ++r) {
            const int sL = q0L + wid * 16 + lhi * 4 + r;
            const int sH = q0H + wid * 16 + lhi * 4 + r;
            const size_t cix = h * 64 + nb * 16 + l15;
            Ao[((size_t)b * SLEN + sL) * DMOD + cix] = f2bf(oL[nb][r] * liL[r]);
            Ao[((size_t)b * SLEN + sH) * DMOD + cix] = f2bf(oH[nb][r] * liH[r]);
        }
}

extern "C" void kernel_launch(void* const* d_in, const int* in_sizes, int n_in,
                              void* d_out, int out_size, void* d_ws, size_t ws_size,
                              hipStream_t stream) {
    const float* q  = (const float*)d_in[0];
    const float* k  = (const float*)d_in[1];
    const float* v  = (const float*)d_in[2];
    const float* Wq = (const float*)d_in[4];
    const float* bq = (const float*)d_in[5];
    const float* Wk = (const float*)d_in[6];
    const float* bk = (const float*)d_in[7];
    const float* Wv = (const float*)d_in[8];
    const float* bv = (const float*)d_in[9];
    const float* Wo = (const float*)d_in[10];
    const float* bo = (const float*)d_in[11];

    // ws layout (ushort units): 4 bf16 W's + Q + K + V^T + attn-out = 75 MB.
    unsigned short* wsp = (unsigned short*)d_ws;
    unsigned short* wqc = wsp;
    unsigned short* wkc = wsp + 1048576;
    unsigned short* wvc = wsp + 2097152;
    unsigned short* woc = wsp + 3145728;
    unsigned short* qb  = wsp + 4194304;
    unsigned short* kb  = wsp + 12582912;
    unsigned short* vtb = wsp + 20971520;
    unsigned short* ao  = wsp + 29360128;

    dim3 gb(256);
    convert_w<<<dim3(512), gb, 0, stream>>>(Wq, Wk, Wv, Wo, wsp);
    gemm_qkv<0><<<dim3(512), gb, 0, stream>>>(q, wqc, bq, qb, EXPC);   // Q pre-scaled
    gemm_qkv<0><<<dim3(512), gb, 0, stream>>>(k, wkc, bk, kb, 1.0f);
    gemm_qkv<1><<<dim3(512), gb, 0, stream>>>(v, wvc, bv, vtb, 1.0f);
    attn_kernel<<<dim3(1024), gb, 0, stream>>>(qb, kb, vtb, ao);
    gemm_out<<<dim3(512), gb, 0, stream>>>(ao, woc, bo, (float*)d_out);
}